// Round 5
// baseline (455.823 us; speedup 1.0000x reference)
//
#include <hip/hip_runtime.h>
#include <hip/hip_bf16.h>
#include <stdint.h>

#define D_MODEL 512
#define NH 8
#define DH 64
#define BB 2
#define SS 4096
#define MTOT (BB*SS)   // 8192

typedef __attribute__((ext_vector_type(8))) short bf16x8;
typedef __attribute__((ext_vector_type(4))) short bf16x4;
typedef __attribute__((ext_vector_type(4))) float f32x4;

#if __has_builtin(__builtin_amdgcn_mfma_f32_16x16x16_bf16)
  #define MFMA16(a,b,c) __builtin_amdgcn_mfma_f32_16x16x16_bf16(a,b,c,0,0,0)
#else
  #define MFMA16(a,b,c) __builtin_amdgcn_mfma_f32_16x16x16bf16_1k(a,b,c,0,0,0)
#endif
#define MFMA32(a,b,c) __builtin_amdgcn_mfma_f32_16x16x32_bf16(a,b,c,0,0,0)

__device__ __forceinline__ unsigned f2b(float f) {
  unsigned u = __float_as_uint(f);
  u += 0x7FFF + ((u >> 16) & 1);   // RNE (finite inputs only)
  return u >> 16;
}

__device__ __forceinline__ uint4 pack8(float4 a, float4 b) {
  uint4 r;
  r.x = f2b(a.x) | (f2b(a.y) << 16);
  r.y = f2b(a.z) | (f2b(a.w) << 16);
  r.z = f2b(b.x) | (f2b(b.y) << 16);
  r.w = f2b(b.z) | (f2b(b.w) << 16);
  return r;
}

// ---------------- GEMM: C[m][n] = sum_k A[m][k]*W[n][k] + bias[n] ----------------
// W: [512,512] fp32 row-major (B^T layout), cast to bf16 during staging.
// mode 0: A fp32.  z<2 : bf16 out[((b*NH+h)*SS+s)*DH+dh]   (Q,K head layout)
//                  z==2: bf16 out[((b*NH+h)*DH+dh)*SS+perm(s)]  (V^T, col-swizzled
//                        within 32-s groups so attn can b128-load MFMA16 A-frags)
// mode 1: A bf16 (Ao). fp32 outf[m*512+n]                  (final output)
struct GemmArgs {
  const void* A[3];
  const float* W[3];
  const float* bias[3];
  unsigned short* out[3];
  float* outf;
  int mode;
};

__global__ __launch_bounds__(256) void gemm_kernel(GemmArgs g) {
  const int z = blockIdx.z;
  const float* __restrict__ bias = g.bias[z];
  unsigned short* __restrict__ out = g.out[z];
  const bool vt = (g.mode == 0) && (z == 2);

  __shared__ __align__(16) unsigned short lA[128][40];  // 32 cols + 8 pad
  __shared__ __align__(16) unsigned short lB[128][40];

  const int t = threadIdx.x;
  const int lane = t & 63;
  const int w = t >> 6;
  const int wr = w >> 1, wc = w & 1;
  const int lrow = lane & 15, quad = lane >> 4;
  const int m0 = blockIdx.y * 128;
  const int n0 = blockIdx.x * 128;

  f32x4 acc[4][4];
  for (int i = 0; i < 4; i++)
    for (int j = 0; j < 4; j++)
      for (int r = 0; r < 4; r++) acc[i][j][r] = 0.f;

  for (int kk = 0; kk < 512; kk += 32) {
#pragma unroll
    for (int i = 0; i < 2; i++) {
      int id = t + i * 256;          // 0..511
      int row = id >> 2;             // 0..127
      int c8 = (id & 3) * 8;         // 0,8,16,24
      if (g.mode == 0) {
        const float* Af = (const float*)g.A[z];
        float4 a0 = *(const float4*)(Af + (size_t)(m0 + row) * 512 + kk + c8);
        float4 a1 = *(const float4*)(Af + (size_t)(m0 + row) * 512 + kk + c8 + 4);
        *(uint4*)&lA[row][c8] = pack8(a0, a1);
      } else {
        const unsigned short* Ab = (const unsigned short*)g.A[z];
        *(uint4*)&lA[row][c8] = *(const uint4*)(Ab + (size_t)(m0 + row) * 512 + kk + c8);
      }
      const float* Wf = g.W[z];
      float4 w0 = *(const float4*)(Wf + (size_t)(n0 + row) * 512 + kk + c8);
      float4 w1 = *(const float4*)(Wf + (size_t)(n0 + row) * 512 + kk + c8 + 4);
      *(uint4*)&lB[row][c8] = pack8(w0, w1);
    }
    __syncthreads();
    bf16x8 af[4], bfr[4];
#pragma unroll
    for (int mt = 0; mt < 4; mt++) af[mt] = *(const bf16x8*)&lA[wr * 64 + mt * 16 + lrow][quad * 8];
#pragma unroll
    for (int nt = 0; nt < 4; nt++) bfr[nt] = *(const bf16x8*)&lB[wc * 64 + nt * 16 + lrow][quad * 8];
#pragma unroll
    for (int mt = 0; mt < 4; mt++)
#pragma unroll
      for (int nt = 0; nt < 4; nt++)
        acc[mt][nt] = MFMA32(af[mt], bfr[nt], acc[mt][nt]);
    __syncthreads();
  }

  float bv[4];
#pragma unroll
  for (int nt = 0; nt < 4; nt++) bv[nt] = bias[n0 + wc * 64 + nt * 16 + lrow];

#pragma unroll
  for (int mt = 0; mt < 4; mt++) {
#pragma unroll
    for (int nt = 0; nt < 4; nt++) {
      const int n = n0 + wc * 64 + nt * 16 + lrow;
      const int mB = m0 + wr * 64 + mt * 16 + quad * 4;   // r=0 row
      float val[4];
#pragma unroll
      for (int r = 0; r < 4; r++) val[r] = acc[mt][nt][r] + bv[nt];

      if (g.mode == 1) {
#pragma unroll
        for (int r = 0; r < 4; r++) g.outf[(size_t)(mB + r) * 512 + n] = val[r];
      } else if (vt) {
        // V^T with within-32-group column swizzle: s=4a+r -> c = (s&~31)+(a&4)+((a&3)<<3)+r
        const int bb = mB >> 12, s = mB & 4095;
        const int a = s >> 2;
        const int c0 = (s & ~31) + (a & 4) + ((a & 3) << 3);
        const int hh = n >> 6, dh = n & 63;
        ushort4 pk = make_ushort4((unsigned short)f2b(val[0]), (unsigned short)f2b(val[1]),
                                  (unsigned short)f2b(val[2]), (unsigned short)f2b(val[3]));
        *(ushort4*)(out + (((size_t)bb * NH + hh) * DH + dh) * SS + c0) = pk;
      } else {
        const int bb = mB >> 12;
        const int hh = n >> 6, dh = n & 63;
#pragma unroll
        for (int r = 0; r < 4; r++) {
          const int s = (mB + r) & 4095;
          out[((((size_t)bb * NH + hh) * SS + s) << 6) + dh] = (unsigned short)f2b(val[r]);
        }
      }
    }
  }
}

// ---------------- flash attention, S^T formulation, LDS-free ----------------
// grid (SS/128=32, NH, BB) = 512 blocks, 128 threads (2 waves), 64 Q-rows/WAVE.
// S^T = K*Q^T: P^T's MFMA C-layout registers are directly a valid K=16 B-operand
// for O^T = V^T*P^T (no LDS round-trip). K/V fragments read straight from
// global (L2/L3-resident working set); no barriers, no LDS at all.
__global__ __launch_bounds__(128) void attn_kernel(const unsigned short* __restrict__ Qh,
                                                   const unsigned short* __restrict__ Kh,
                                                   const unsigned short* __restrict__ Vt,
                                                   unsigned short* __restrict__ Ao) {
  const int t = threadIdx.x;
  const int lane = t & 63;
  const int w = t >> 6;
  const int lrow = lane & 15, quad = lane >> 4;
  const int h = blockIdx.y, b = blockIdx.z;
  const size_t kb = ((size_t)b * NH + h) * SS * DH;   // Q,K base: [s][dh]
  const size_t vb = ((size_t)b * NH + h) * DH * SS;   // Vt base: [dh][s'] (swizzled)
  const int qrow0 = blockIdx.x * 128 + w * 64;

  // Q as B-operand frags: qf[ti][c] = Q[i=qrow0+ti*16+lrow][d=c*32+quad*8+e]
  bf16x8 qf[4][2];
#pragma unroll
  for (int ti = 0; ti < 4; ti++) {
    const unsigned short* qp = Qh + kb + (size_t)(qrow0 + ti * 16 + lrow) * DH + quad * 8;
    qf[ti][0] = *(const bf16x8*)qp;
    qf[ti][1] = *(const bf16x8*)(qp + 32);
  }

  // O^T accumulators: o[ti][nt] reg r = O[i=ti*16+lrow][d=nt*16+quad*4+r]
  f32x4 o[4][4];
  float lsum[4] = {0.f, 0.f, 0.f, 0.f};
#pragma unroll
  for (int ti = 0; ti < 4; ti++)
    for (int nt = 0; nt < 4; nt++)
      for (int r = 0; r < 4; r++) o[ti][nt][r] = 0.f;

  const unsigned short* __restrict__ Kp = Kh + kb + (size_t)lrow * DH + quad * 8;
  const unsigned short* __restrict__ Vp = Vt + vb + (size_t)lrow * SS + quad * 8;

  for (int jt = 0; jt < SS / 64; jt++) {
    const int jb = jt * 64;
#pragma unroll
    for (int half = 0; half < 2; half++) {
      // S^T = K * Q^T for j-rows [jb+half*32, +32); P packed to bf16x4 B-frags
      bf16x4 pf[2][4];
#pragma unroll
      for (int u = 0; u < 2; u++) {
        const int ntj = half * 2 + u;
        const unsigned short* kp = Kp + (size_t)(jb + ntj * 16) * DH;
        bf16x8 k0 = *(const bf16x8*)kp;
        bf16x8 k1 = *(const bf16x8*)(kp + 32);
#pragma unroll
        for (int ti = 0; ti < 4; ti++) {
          f32x4 s;
          for (int r = 0; r < 4; r++) s[r] = 0.f;
          s = MFMA32(k0, qf[ti][0], s);
          s = MFMA32(k1, qf[ti][1], s);
          float p0 = __expf(fmaf(s[0], 0.125f, -8.0f));
          float p1 = __expf(fmaf(s[1], 0.125f, -8.0f));
          float p2 = __expf(fmaf(s[2], 0.125f, -8.0f));
          float p3 = __expf(fmaf(s[3], 0.125f, -8.0f));
          lsum[ti] += (p0 + p1) + (p2 + p3);
          bf16x4 pk;
          pk[0] = (short)f2b(p0); pk[1] = (short)f2b(p1);
          pk[2] = (short)f2b(p2); pk[3] = (short)f2b(p3);
          pf[u][ti] = pk;
        }
      }
      // O^T += V^T * P^T  (V b128 = two MFMA16 A-frags thanks to the swizzle)
#pragma unroll
      for (int nt = 0; nt < 4; nt++) {
        bf16x8 vv = *(const bf16x8*)(Vp + (size_t)(nt * 16) * SS + jb + half * 32);
        bf16x4 v0 = __builtin_shufflevector(vv, vv, 0, 1, 2, 3);
        bf16x4 v1 = __builtin_shufflevector(vv, vv, 4, 5, 6, 7);
#pragma unroll
        for (int ti = 0; ti < 4; ti++)
          o[ti][nt] = MFMA16(v0, pf[0][ti], o[ti][nt]);
#pragma unroll
        for (int ti = 0; ti < 4; ti++)
          o[ti][nt] = MFMA16(v1, pf[1][ti], o[ti][nt]);
      }
    }
  }

  // finalize: l = cross-quad sum; O /= l; store Ao[b*SS+s][h*64+d]
#pragma unroll
  for (int ti = 0; ti < 4; ti++) {
    float l = lsum[ti];
    l += __shfl_xor(l, 16);
    l += __shfl_xor(l, 32);
    const float inv = __builtin_amdgcn_rcpf(l);
    const int si = qrow0 + ti * 16 + lrow;
    unsigned short* dst = Ao + ((size_t)(b * SS + si)) * D_MODEL + h * DH;
#pragma unroll
    for (int nt = 0; nt < 4; nt++) {
      ushort4 pk = make_ushort4((unsigned short)f2b(o[ti][nt][0] * inv),
                                (unsigned short)f2b(o[ti][nt][1] * inv),
                                (unsigned short)f2b(o[ti][nt][2] * inv),
                                (unsigned short)f2b(o[ti][nt][3] * inv));
      *(ushort4*)(dst + nt * 16 + quad * 4) = pk;
    }
  }
}

// ---------------- launch ----------------
extern "C" void kernel_launch(void* const* d_in, const int* in_sizes, int n_in,
                              void* d_out, int out_size, void* d_ws, size_t ws_size,
                              hipStream_t stream) {
  const float* q  = (const float*)d_in[0];
  const float* k  = (const float*)d_in[1];
  const float* v  = (const float*)d_in[2];
  const float* Wq = (const float*)d_in[3];
  const float* bq = (const float*)d_in[4];
  const float* Wk = (const float*)d_in[5];
  const float* bk = (const float*)d_in[6];
  const float* Wv = (const float*)d_in[7];
  const float* bv = (const float*)d_in[8];
  const float* Wo = (const float*)d_in[9];
  const float* bo = (const float*)d_in[10];

  const size_t NX = (size_t)MTOT * D_MODEL;     // 4,194,304

  char* p = (char*)d_ws;
  unsigned short* Qh  = (unsigned short*)p; p += NX * 2;
  unsigned short* Kh  = (unsigned short*)p; p += NX * 2;
  unsigned short* Vtg = (unsigned short*)p; p += NX * 2;
  unsigned short* Ao  = (unsigned short*)p; p += NX * 2;

  GemmArgs pa;
  pa.A[0] = q; pa.A[1] = k; pa.A[2] = v;
  pa.W[0] = Wq; pa.W[1] = Wk; pa.W[2] = Wv;
  pa.bias[0] = bq; pa.bias[1] = bk; pa.bias[2] = bv;
  pa.out[0] = Qh; pa.out[1] = Kh; pa.out[2] = Vtg;
  pa.outf = nullptr;
  pa.mode = 0;
  gemm_kernel<<<dim3(4, 64, 3), 256, 0, stream>>>(pa);

  attn_kernel<<<dim3(SS / 128, NH, BB), 128, 0, stream>>>(Qh, Kh, Vtg, Ao);

  GemmArgs oa;
  oa.A[0] = Ao; oa.A[1] = Ao; oa.A[2] = Ao;
  oa.W[0] = Wo; oa.W[1] = Wo; oa.W[2] = Wo;
  oa.bias[0] = bo; oa.bias[1] = bo; oa.bias[2] = bo;
  oa.out[0] = nullptr; oa.out[1] = nullptr; oa.out[2] = nullptr;
  oa.outf = (float*)d_out;
  oa.mode = 1;
  gemm_kernel<<<dim3(4, 64, 1), 256, 0, stream>>>(oa);
}

// Round 6
// 354.207 us; speedup vs baseline: 1.2869x; 1.2869x over previous
//
#include <hip/hip_runtime.h>
#include <hip/hip_bf16.h>
#include <stdint.h>

#define D_MODEL 512
#define NH 8
#define DH 64
#define BB 2
#define SS 4096
#define MTOT (BB*SS)   // 8192

typedef __attribute__((ext_vector_type(8))) short bf16x8;
typedef __attribute__((ext_vector_type(4))) short bf16x4;
typedef __attribute__((ext_vector_type(4))) float f32x4;

#if __has_builtin(__builtin_amdgcn_mfma_f32_16x16x16_bf16)
  #define MFMA16(a,b,c) __builtin_amdgcn_mfma_f32_16x16x16_bf16(a,b,c,0,0,0)
#else
  #define MFMA16(a,b,c) __builtin_amdgcn_mfma_f32_16x16x16bf16_1k(a,b,c,0,0,0)
#endif
#define MFMA32(a,b,c) __builtin_amdgcn_mfma_f32_16x16x32_bf16(a,b,c,0,0,0)

#if __has_builtin(__builtin_amdgcn_exp2f)
  #define EXP2F(x) __builtin_amdgcn_exp2f(x)
#else
  #define EXP2F(x) __expf((x) * 0.6931471805599453f)
#endif

// Q pre-scale folds score*0.125 AND the log2e of exp into the projection:
// p = exp(s/8 - 8) = exp2(s*0.125*log2e - 8*log2e)
#define QSCALE 0.18033688011112042f   // 0.125 * log2(e)
#define EXPOFF 11.541560327679939f    // 8 * log2(e)

__device__ __forceinline__ unsigned f2b(float f) {
  unsigned u = __float_as_uint(f);
  u += 0x7FFF + ((u >> 16) & 1);   // RNE (finite inputs only)
  return u >> 16;
}

__device__ __forceinline__ uint4 pack8(float4 a, float4 b) {
  uint4 r;
  r.x = f2b(a.x) | (f2b(a.y) << 16);
  r.y = f2b(a.z) | (f2b(a.w) << 16);
  r.z = f2b(b.x) | (f2b(b.y) << 16);
  r.w = f2b(b.z) | (f2b(b.w) << 16);
  return r;
}

// ---------------- GEMM: C[m][n] = sum_k A[m][k]*W[n][k] + bias[n] ----------------
// W: [512,512] fp32 row-major (B^T layout), cast to bf16 during staging.
// mode 0: A fp32.  z==0: Q, scaled by QSCALE, bf16 out[((b*NH+h)*SS+s)*DH+dh]
//                  z==1: K,                   bf16 out[((b*NH+h)*SS+s)*DH+dh]
//                  z==2: V^T col-swizzled     bf16 out[((b*NH+h)*DH+dh)*SS+perm(s)]
// mode 1: A bf16 (Ao). fp32 outf[m*512+n]  (final output)
struct GemmArgs {
  const void* A[3];
  const float* W[3];
  const float* bias[3];
  unsigned short* out[3];
  float* outf;
  int mode;
};

__global__ __launch_bounds__(256) void gemm_kernel(GemmArgs g) {
  const int z = blockIdx.z;
  const float* __restrict__ bias = g.bias[z];
  unsigned short* __restrict__ out = g.out[z];
  const bool vt = (g.mode == 0) && (z == 2);
  const float osc = (g.mode == 0 && z == 0) ? QSCALE : 1.0f;

  __shared__ __align__(16) unsigned short lA[128][40];  // 32 cols + 8 pad
  __shared__ __align__(16) unsigned short lB[128][40];

  const int t = threadIdx.x;
  const int lane = t & 63;
  const int w = t >> 6;
  const int wr = w >> 1, wc = w & 1;
  const int lrow = lane & 15, quad = lane >> 4;
  const int m0 = blockIdx.y * 128;
  const int n0 = blockIdx.x * 128;

  f32x4 acc[4][4];
  for (int i = 0; i < 4; i++)
    for (int j = 0; j < 4; j++)
      for (int r = 0; r < 4; r++) acc[i][j][r] = 0.f;

  for (int kk = 0; kk < 512; kk += 32) {
#pragma unroll
    for (int i = 0; i < 2; i++) {
      int id = t + i * 256;          // 0..511
      int row = id >> 2;             // 0..127
      int c8 = (id & 3) * 8;         // 0,8,16,24
      if (g.mode == 0) {
        const float* Af = (const float*)g.A[z];
        float4 a0 = *(const float4*)(Af + (size_t)(m0 + row) * 512 + kk + c8);
        float4 a1 = *(const float4*)(Af + (size_t)(m0 + row) * 512 + kk + c8 + 4);
        *(uint4*)&lA[row][c8] = pack8(a0, a1);
      } else {
        const unsigned short* Ab = (const unsigned short*)g.A[z];
        *(uint4*)&lA[row][c8] = *(const uint4*)(Ab + (size_t)(m0 + row) * 512 + kk + c8);
      }
      const float* Wf = g.W[z];
      float4 w0 = *(const float4*)(Wf + (size_t)(n0 + row) * 512 + kk + c8);
      float4 w1 = *(const float4*)(Wf + (size_t)(n0 + row) * 512 + kk + c8 + 4);
      *(uint4*)&lB[row][c8] = pack8(w0, w1);
    }
    __syncthreads();
    bf16x8 af[4], bfr[4];
#pragma unroll
    for (int mt = 0; mt < 4; mt++) af[mt] = *(const bf16x8*)&lA[wr * 64 + mt * 16 + lrow][quad * 8];
#pragma unroll
    for (int nt = 0; nt < 4; nt++) bfr[nt] = *(const bf16x8*)&lB[wc * 64 + nt * 16 + lrow][quad * 8];
#pragma unroll
    for (int mt = 0; mt < 4; mt++)
#pragma unroll
      for (int nt = 0; nt < 4; nt++)
        acc[mt][nt] = MFMA32(af[mt], bfr[nt], acc[mt][nt]);
    __syncthreads();
  }

  float bv[4];
#pragma unroll
  for (int nt = 0; nt < 4; nt++) bv[nt] = bias[n0 + wc * 64 + nt * 16 + lrow];

#pragma unroll
  for (int mt = 0; mt < 4; mt++) {
#pragma unroll
    for (int nt = 0; nt < 4; nt++) {
      const int n = n0 + wc * 64 + nt * 16 + lrow;
      const int mB = m0 + wr * 64 + mt * 16 + quad * 4;   // r=0 row
      float val[4];
#pragma unroll
      for (int r = 0; r < 4; r++) val[r] = (acc[mt][nt][r] + bv[nt]) * osc;

      if (g.mode == 1) {
#pragma unroll
        for (int r = 0; r < 4; r++) g.outf[(size_t)(mB + r) * 512 + n] = val[r];
      } else if (vt) {
        // V^T within-32-group swizzle: s=4a+r -> c = (s&~31)+(a&4)+((a&3)<<3)+r
        const int bb = mB >> 12, s = mB & 4095;
        const int a = s >> 2;
        const int c0 = (s & ~31) + (a & 4) + ((a & 3) << 3);
        const int hh = n >> 6, dh = n & 63;
        ushort4 pk = make_ushort4((unsigned short)f2b(val[0]), (unsigned short)f2b(val[1]),
                                  (unsigned short)f2b(val[2]), (unsigned short)f2b(val[3]));
        *(ushort4*)(out + (((size_t)bb * NH + hh) * DH + dh) * SS + c0) = pk;
      } else {
        const int bb = mB >> 12;
        const int hh = n >> 6, dh = n & 63;
#pragma unroll
        for (int r = 0; r < 4; r++) {
          const int s = (mB + r) & 4095;
          out[((((size_t)bb * NH + hh) * SS + s) << 6) + dh] = (unsigned short)f2b(val[r]);
        }
      }
    }
  }
}

// ---------------- flash attention, S^T formulation ----------------
// grid (SS/128=32, NH, BB)=512 blocks, 256 threads (4 waves), 32 Q-rows/wave.
// 8 waves/CU (2/SIMD). K double-buffered in LDS (1 barrier/jt, reg prefetch);
// V read direct from global (swizzled layout -> b128 = two MFMA16 A-frags).
// P^T stays in registers (S^T C-layout == K=16 B-operand); l via ones-A MFMA.
__global__ __launch_bounds__(256, 2) void attn_kernel(const unsigned short* __restrict__ Qh,
                                                      const unsigned short* __restrict__ Kh,
                                                      const unsigned short* __restrict__ Vt,
                                                      unsigned short* __restrict__ Ao) {
  __shared__ __align__(16) unsigned short lK[2][64][72];

  const int t = threadIdx.x;
  const int lane = t & 63;
  const int w = t >> 6;
  const int lrow = lane & 15, quad = lane >> 4;
  const int h = blockIdx.y, b = blockIdx.z;
  const size_t kb = ((size_t)b * NH + h) * SS * DH;   // Q,K: [s][dh]
  const size_t vb = ((size_t)b * NH + h) * DH * SS;   // V^T: [dh][s'] swizzled
  const int qrow0 = blockIdx.x * 128 + w * 32;

  // Q as B-operand frags: qf[ti][c] = Q[i=qrow0+ti*16+lrow][d=c*32+quad*8+e]
  bf16x8 qf[2][2];
#pragma unroll
  for (int ti = 0; ti < 2; ti++) {
    const unsigned short* qp = Qh + kb + (size_t)(qrow0 + ti * 16 + lrow) * DH + quad * 8;
    qf[ti][0] = *(const bf16x8*)qp;
    qf[ti][1] = *(const bf16x8*)(qp + 32);
  }

  bf16x4 ones;
#pragma unroll
  for (int i = 0; i < 4; i++) ones[i] = (short)0x3F80;

  f32x4 o[2][4], lac[2];
#pragma unroll
  for (int ti = 0; ti < 2; ti++) {
    for (int nt = 0; nt < 4; nt++)
      for (int r = 0; r < 4; r++) o[ti][nt][r] = 0.f;
    for (int r = 0; r < 4; r++) lac[ti][r] = 0.f;
  }

  const unsigned short* __restrict__ Kg = Kh + kb;
  const unsigned short* __restrict__ Vp = Vt + vb + (size_t)lrow * SS + quad * 8;

  const int r0 = t >> 3, r1 = (t + 256) >> 3;      // staging rows
  const int cs = (t & 7) * 8;                      // staging col

  // stage tile 0
  uint4 kreg0 = *(const uint4*)(Kg + (size_t)r0 * DH + cs);
  uint4 kreg1 = *(const uint4*)(Kg + (size_t)r1 * DH + cs);
  *(uint4*)&lK[0][r0][cs] = kreg0;
  *(uint4*)&lK[0][r1][cs] = kreg1;

  for (int jt = 0; jt < SS / 64; jt++) {
    const int jb = jt * 64;
    __syncthreads();   // lK[jt&1] ready for all waves
    // prefetch next K tile into registers
    {
      const int nb = (jt + 1 < SS / 64 ? jt + 1 : jt) * 64;
      kreg0 = *(const uint4*)(Kg + (size_t)(nb + r0) * DH + cs);
      kreg1 = *(const uint4*)(Kg + (size_t)(nb + r1) * DH + cs);
    }

    // S^T = K*Q^T per 16-j group; p = exp2(s - EXPOFF); pack to bf16x4 B-frags
    bf16x4 pf[4][2];
#pragma unroll
    for (int ntj = 0; ntj < 4; ntj++) {
      bf16x8 k0 = *(const bf16x8*)&lK[jt & 1][ntj * 16 + lrow][quad * 8];
      bf16x8 k1 = *(const bf16x8*)&lK[jt & 1][ntj * 16 + lrow][32 + quad * 8];
#pragma unroll
      for (int ti = 0; ti < 2; ti++) {
        f32x4 s;
        for (int r = 0; r < 4; r++) s[r] = 0.f;
        s = MFMA32(k0, qf[ti][0], s);
        s = MFMA32(k1, qf[ti][1], s);
        unsigned u0 = __float_as_uint(EXP2F(s[0] - EXPOFF)) + 0x8000u;
        unsigned u1 = __float_as_uint(EXP2F(s[1] - EXPOFF)) + 0x8000u;
        unsigned u2 = __float_as_uint(EXP2F(s[2] - EXPOFF)) + 0x8000u;
        unsigned u3 = __float_as_uint(EXP2F(s[3] - EXPOFF)) + 0x8000u;
        uint2 pp;
        pp.x = __builtin_amdgcn_perm(u1, u0, 0x07060302u);
        pp.y = __builtin_amdgcn_perm(u3, u2, 0x07060302u);
        pf[ntj][ti] = __builtin_bit_cast(bf16x4, pp);
      }
    }

    // l += 1 * P^T  (ones as A-operand; C col = Q-row)
#pragma unroll
    for (int ks = 0; ks < 4; ks++)
#pragma unroll
      for (int ti = 0; ti < 2; ti++)
        lac[ti] = MFMA16(ones, pf[ks][ti], lac[ti]);

    // O^T += V^T * P^T  (V b128 = two MFMA16 A-frags via the store swizzle)
#pragma unroll
    for (int nt = 0; nt < 4; nt++) {
#pragma unroll
      for (int half = 0; half < 2; half++) {
        bf16x8 vv = *(const bf16x8*)(Vp + (size_t)(nt * 16) * SS + jb + half * 32);
        bf16x4 v0 = __builtin_shufflevector(vv, vv, 0, 1, 2, 3);
        bf16x4 v1 = __builtin_shufflevector(vv, vv, 4, 5, 6, 7);
#pragma unroll
        for (int ti = 0; ti < 2; ti++)
          o[ti][nt] = MFMA16(v0, pf[half * 2 + 0][ti], o[ti][nt]);
#pragma unroll
        for (int ti = 0; ti < 2; ti++)
          o[ti][nt] = MFMA16(v1, pf[half * 2 + 1][ti], o[ti][nt]);
      }
    }

    // write prefetched tile to the other buffer (barrier next iter covers it)
    *(uint4*)&lK[(jt + 1) & 1][r0][cs] = kreg0;
    *(uint4*)&lK[(jt + 1) & 1][r1][cs] = kreg1;
  }

  // finalize: l from lac (all regs equal); O /= l; store Ao[b*SS+s][h*64+d]
#pragma unroll
  for (int ti = 0; ti < 2; ti++) {
    const float inv = __builtin_amdgcn_rcpf(lac[ti][0]);
    const int si = qrow0 + ti * 16 + lrow;
    unsigned short* dst = Ao + ((size_t)(b * SS + si)) * D_MODEL + h * DH;
#pragma unroll
    for (int nt = 0; nt < 4; nt++) {
      ushort4 pk = make_ushort4((unsigned short)f2b(o[ti][nt][0] * inv),
                                (unsigned short)f2b(o[ti][nt][1] * inv),
                                (unsigned short)f2b(o[ti][nt][2] * inv),
                                (unsigned short)f2b(o[ti][nt][3] * inv));
      *(ushort4*)(dst + nt * 16 + quad * 4) = pk;
    }
  }
}

// ---------------- launch ----------------
extern "C" void kernel_launch(void* const* d_in, const int* in_sizes, int n_in,
                              void* d_out, int out_size, void* d_ws, size_t ws_size,
                              hipStream_t stream) {
  const float* q  = (const float*)d_in[0];
  const float* k  = (const float*)d_in[1];
  const float* v  = (const float*)d_in[2];
  const float* Wq = (const float*)d_in[3];
  const float* bq = (const float*)d_in[4];
  const float* Wk = (const float*)d_in[5];
  const float* bk = (const float*)d_in[6];
  const float* Wv = (const float*)d_in[7];
  const float* bv = (const float*)d_in[8];
  const float* Wo = (const float*)d_in[9];
  const float* bo = (const float*)d_in[10];

  const size_t NX = (size_t)MTOT * D_MODEL;     // 4,194,304

  char* p = (char*)d_ws;
  unsigned short* Qh  = (unsigned short*)p; p += NX * 2;
  unsigned short* Kh  = (unsigned short*)p; p += NX * 2;
  unsigned short* Vtg = (unsigned short*)p; p += NX * 2;
  unsigned short* Ao  = (unsigned short*)p; p += NX * 2;

  GemmArgs pa;
  pa.A[0] = q; pa.A[1] = k; pa.A[2] = v;
  pa.W[0] = Wq; pa.W[1] = Wk; pa.W[2] = Wv;
  pa.bias[0] = bq; pa.bias[1] = bk; pa.bias[2] = bv;
  pa.out[0] = Qh; pa.out[1] = Kh; pa.out[2] = Vtg;
  pa.outf = nullptr;
  pa.mode = 0;
  gemm_kernel<<<dim3(4, 64, 3), 256, 0, stream>>>(pa);

  attn_kernel<<<dim3(SS / 128, NH, BB), 256, 0, stream>>>(Qh, Kh, Vtg, Ao);

  GemmArgs oa;
  oa.A[0] = Ao; oa.A[1] = Ao; oa.A[2] = Ao;
  oa.W[0] = Wo; oa.W[1] = Wo; oa.W[2] = Wo;
  oa.bias[0] = bo; oa.bias[1] = bo; oa.bias[2] = bo;
  oa.out[0] = nullptr; oa.out[1] = nullptr; oa.out[2] = nullptr;
  oa.outf = (float*)d_out;
  oa.mode = 1;
  gemm_kernel<<<dim3(4, 64, 1), 256, 0, stream>>>(oa);
}

// Round 7
// 298.817 us; speedup vs baseline: 1.5254x; 1.1854x over previous
//
#include <hip/hip_runtime.h>
#include <hip/hip_bf16.h>
#include <stdint.h>

#define D_MODEL 512
#define NH 8
#define DH 64
#define BB 2
#define SS 4096
#define MTOT (BB*SS)   // 8192

typedef __attribute__((ext_vector_type(8))) short bf16x8;
typedef __attribute__((ext_vector_type(4))) short bf16x4;
typedef __attribute__((ext_vector_type(4))) float f32x4;

#if __has_builtin(__builtin_amdgcn_mfma_f32_16x16x16_bf16)
  #define MFMA16(a,b,c) __builtin_amdgcn_mfma_f32_16x16x16_bf16(a,b,c,0,0,0)
#else
  #define MFMA16(a,b,c) __builtin_amdgcn_mfma_f32_16x16x16bf16_1k(a,b,c,0,0,0)
#endif
#define MFMA32(a,b,c) __builtin_amdgcn_mfma_f32_16x16x32_bf16(a,b,c,0,0,0)

#if __has_builtin(__builtin_amdgcn_exp2f)
  #define EXP2F(x) __builtin_amdgcn_exp2f(x)
#else
  #define EXP2F(x) __expf((x) * 0.6931471805599453f)
#endif

// p = exp(s/8 - 8) = exp2(s*0.125*log2e - 8*log2e); 0.125*log2e folded into Q proj.
#define QSCALE 0.18033688011112042f   // 0.125 * log2(e)
#define EXPOFF 11.541560327679939f    // 8 * log2(e)

__device__ __forceinline__ unsigned f2b(float f) {
  unsigned u = __float_as_uint(f);
  u += 0x7FFF + ((u >> 16) & 1);   // RNE (finite inputs only)
  return u >> 16;
}

__device__ __forceinline__ uint4 pack8(float4 a, float4 b) {
  uint4 r;
  r.x = f2b(a.x) | (f2b(a.y) << 16);
  r.y = f2b(a.z) | (f2b(a.w) << 16);
  r.z = f2b(b.x) | (f2b(b.y) << 16);
  r.w = f2b(b.z) | (f2b(b.w) << 16);
  return r;
}

// ---------------- GEMM: C[m][n] = sum_k A[m][k]*W[n][k] + bias[n] ----------------
// Tile 64m x 128n, grid (4, 128, z). W fp32 cast to bf16 during staging.
// mode 0: A fp32. z==0: Q*QSCALE -> [((b*NH+h)*SS+s)*DH+dh]
//                 z==1: K        -> same layout
//                 z==2: V^T col-swizzled -> [((b*NH+h)*DH+dh)*SS+perm(s)]
// mode 1: A = combine of two fp32 partial-O slabs / (la+lb); fp32 outf[m*512+n]
struct GemmArgs {
  const void* A[3];
  const float* W[3];
  const float* bias[3];
  unsigned short* out[3];
  float* outf;
  const float* Oa; const float* Ob;
  const float* la; const float* lb;
  int mode;
};

__global__ __launch_bounds__(256, 4) void gemm_kernel(GemmArgs g) {
  const int z = blockIdx.z;
  const float* __restrict__ bias = g.bias[z];
  unsigned short* __restrict__ out = g.out[z];
  const bool vt = (g.mode == 0) && (z == 2);
  const float osc = (g.mode == 0 && z == 0) ? QSCALE : 1.0f;

  __shared__ __align__(16) unsigned short lA[64][40];
  __shared__ __align__(16) unsigned short lB[128][40];

  const int t = threadIdx.x;
  const int lane = t & 63;
  const int w = t >> 6;
  const int wr = w >> 1, wc = w & 1;     // wave covers m: wr*32+32, n: wc*64+64
  const int lrow = lane & 15, quad = lane >> 4;
  const int m0 = blockIdx.y * 64;
  const int n0 = blockIdx.x * 128;

  f32x4 acc[2][4];
  for (int i = 0; i < 2; i++)
    for (int j = 0; j < 4; j++)
      for (int r = 0; r < 4; r++) acc[i][j][r] = 0.f;

  const int rowA = t >> 2, c8A = (t & 3) * 8;   // 64 rows x 4 chunks

  for (int kk = 0; kk < 512; kk += 32) {
    // ---- stage A (64x32) ----
    if (g.mode == 0) {
      const float* Af = (const float*)g.A[z];
      float4 a0 = *(const float4*)(Af + (size_t)(m0 + rowA) * 512 + kk + c8A);
      float4 a1 = *(const float4*)(Af + (size_t)(m0 + rowA) * 512 + kk + c8A + 4);
      *(uint4*)&lA[rowA][c8A] = pack8(a0, a1);
    } else {
      const int m = m0 + rowA;
      const int k = kk + c8A;
      const int hh = k >> 6;
      const float inv = __builtin_amdgcn_rcpf(g.la[(size_t)m * NH + hh] +
                                              g.lb[(size_t)m * NH + hh]);
      float4 a0 = *(const float4*)(g.Oa + (size_t)m * 512 + k);
      float4 a1 = *(const float4*)(g.Oa + (size_t)m * 512 + k + 4);
      float4 b0 = *(const float4*)(g.Ob + (size_t)m * 512 + k);
      float4 b1 = *(const float4*)(g.Ob + (size_t)m * 512 + k + 4);
      float4 s0 = make_float4((a0.x + b0.x) * inv, (a0.y + b0.y) * inv,
                              (a0.z + b0.z) * inv, (a0.w + b0.w) * inv);
      float4 s1 = make_float4((a1.x + b1.x) * inv, (a1.y + b1.y) * inv,
                              (a1.z + b1.z) * inv, (a1.w + b1.w) * inv);
      *(uint4*)&lA[rowA][c8A] = pack8(s0, s1);
    }
    // ---- stage B/W (128x32) ----
#pragma unroll
    for (int i = 0; i < 2; i++) {
      int id = t + i * 256;
      int row = id >> 2;
      int c8 = (id & 3) * 8;
      const float* Wf = g.W[z];
      float4 w0 = *(const float4*)(Wf + (size_t)(n0 + row) * 512 + kk + c8);
      float4 w1 = *(const float4*)(Wf + (size_t)(n0 + row) * 512 + kk + c8 + 4);
      *(uint4*)&lB[row][c8] = pack8(w0, w1);
    }
    __syncthreads();
    bf16x8 af[2], bfr[4];
#pragma unroll
    for (int mt = 0; mt < 2; mt++) af[mt] = *(const bf16x8*)&lA[wr * 32 + mt * 16 + lrow][quad * 8];
#pragma unroll
    for (int nt = 0; nt < 4; nt++) bfr[nt] = *(const bf16x8*)&lB[wc * 64 + nt * 16 + lrow][quad * 8];
#pragma unroll
    for (int mt = 0; mt < 2; mt++)
#pragma unroll
      for (int nt = 0; nt < 4; nt++)
        acc[mt][nt] = MFMA32(af[mt], bfr[nt], acc[mt][nt]);
    __syncthreads();
  }

  float bv[4];
#pragma unroll
  for (int nt = 0; nt < 4; nt++) bv[nt] = bias[n0 + wc * 64 + nt * 16 + lrow];

#pragma unroll
  for (int mt = 0; mt < 2; mt++) {
#pragma unroll
    for (int nt = 0; nt < 4; nt++) {
      const int n = n0 + wc * 64 + nt * 16 + lrow;
      const int mB = m0 + wr * 32 + mt * 16 + quad * 4;   // r=0 row
      float val[4];
#pragma unroll
      for (int r = 0; r < 4; r++) val[r] = (acc[mt][nt][r] + bv[nt]) * osc;

      if (g.mode == 1) {
#pragma unroll
        for (int r = 0; r < 4; r++) g.outf[(size_t)(mB + r) * 512 + n] = val[r];
      } else if (vt) {
        // V^T within-32-group swizzle: s=4a+r -> c = (s&~31)+(a&4)+((a&3)<<3)+r
        const int bb = mB >> 12, s = mB & 4095;
        const int a = s >> 2;
        const int c0 = (s & ~31) + (a & 4) + ((a & 3) << 3);
        const int hh = n >> 6, dh = n & 63;
        ushort4 pk = make_ushort4((unsigned short)f2b(val[0]), (unsigned short)f2b(val[1]),
                                  (unsigned short)f2b(val[2]), (unsigned short)f2b(val[3]));
        *(ushort4*)(out + (((size_t)bb * NH + hh) * DH + dh) * SS + c0) = pk;
      } else {
        const int bb = mB >> 12;
        const int hh = n >> 6, dh = n & 63;
#pragma unroll
        for (int r = 0; r < 4; r++) {
          const int s = (mB + r) & 4095;
          out[((((size_t)bb * NH + hh) * SS + s) << 6) + dh] = (unsigned short)f2b(val[r]);
        }
      }
    }
  }
}

// ---------------- flash attention, S^T formulation, j-split ----------------
// grid (64, NH, BB): blockIdx.x = qtile*2 + jhalf. 256 thr (4 waves), 32 Q-rows/wave,
// each block covers 32 j-tiles (half the sequence) -> 1024 blocks, 16 waves/CU.
// Unnormalized fp32 partial O + partial l written per jhalf slab; combined exactly
// in the out-GEMM (fixed-max softmax => partials add).
__global__ __launch_bounds__(256, 4) void attn_kernel(const unsigned short* __restrict__ Qh,
                                                      const unsigned short* __restrict__ Kh,
                                                      const unsigned short* __restrict__ Vt,
                                                      float* __restrict__ Op0,
                                                      float* __restrict__ Op1,
                                                      float* __restrict__ lp0,
                                                      float* __restrict__ lp1) {
  __shared__ __align__(16) unsigned short lK[2][64][72];

  const int t = threadIdx.x;
  const int lane = t & 63;
  const int w = t >> 6;
  const int lrow = lane & 15, quad = lane >> 4;
  const int h = blockIdx.y, b = blockIdx.z;
  const int qtile = blockIdx.x >> 1, jhalf = blockIdx.x & 1;
  const size_t kb = ((size_t)b * NH + h) * SS * DH;   // Q,K: [s][dh]
  const size_t vb = ((size_t)b * NH + h) * DH * SS;   // V^T: [dh][s'] swizzled
  const int qrow0 = qtile * 128 + w * 32;
  float* __restrict__ Op = jhalf ? Op1 : Op0;
  float* __restrict__ lp = jhalf ? lp1 : lp0;
  const int jt0 = jhalf * 32, jt1 = jt0 + 32;

  bf16x8 qf[2][2];
#pragma unroll
  for (int ti = 0; ti < 2; ti++) {
    const unsigned short* qp = Qh + kb + (size_t)(qrow0 + ti * 16 + lrow) * DH + quad * 8;
    qf[ti][0] = *(const bf16x8*)qp;
    qf[ti][1] = *(const bf16x8*)(qp + 32);
  }

  bf16x4 ones;
#pragma unroll
  for (int i = 0; i < 4; i++) ones[i] = (short)0x3F80;

  f32x4 o[2][4], lac[2];
#pragma unroll
  for (int ti = 0; ti < 2; ti++) {
    for (int nt = 0; nt < 4; nt++)
      for (int r = 0; r < 4; r++) o[ti][nt][r] = 0.f;
    for (int r = 0; r < 4; r++) lac[ti][r] = 0.f;
  }

  const unsigned short* __restrict__ Kg = Kh + kb;
  const unsigned short* __restrict__ Vp = Vt + vb + (size_t)lrow * SS + quad * 8;

  const int r0 = t >> 3, r1 = (t + 256) >> 3;      // staging rows
  const int cs = (t & 7) * 8;                      // staging col

  // stage first tile (jt0 is even -> buffer parity jt&1 starts at 0)
  uint4 kreg0 = *(const uint4*)(Kg + (size_t)(jt0 * 64 + r0) * DH + cs);
  uint4 kreg1 = *(const uint4*)(Kg + (size_t)(jt0 * 64 + r1) * DH + cs);
  *(uint4*)&lK[0][r0][cs] = kreg0;
  *(uint4*)&lK[0][r1][cs] = kreg1;

  for (int jt = jt0; jt < jt1; jt++) {
    const int jb = jt * 64;
    __syncthreads();   // lK[jt&1] ready for all waves
    {
      const int nb = (jt + 1 < jt1 ? jt + 1 : jt) * 64;
      kreg0 = *(const uint4*)(Kg + (size_t)(nb + r0) * DH + cs);
      kreg1 = *(const uint4*)(Kg + (size_t)(nb + r1) * DH + cs);
    }

    // S^T = K*Q^T per 16-j group; p = exp2(s - EXPOFF); pack to bf16x4 B-frags
    bf16x4 pf[4][2];
#pragma unroll
    for (int ntj = 0; ntj < 4; ntj++) {
      bf16x8 k0 = *(const bf16x8*)&lK[jt & 1][ntj * 16 + lrow][quad * 8];
      bf16x8 k1 = *(const bf16x8*)&lK[jt & 1][ntj * 16 + lrow][32 + quad * 8];
#pragma unroll
      for (int ti = 0; ti < 2; ti++) {
        f32x4 s;
        for (int r = 0; r < 4; r++) s[r] = 0.f;
        s = MFMA32(k0, qf[ti][0], s);
        s = MFMA32(k1, qf[ti][1], s);
        unsigned u0 = __float_as_uint(EXP2F(s[0] - EXPOFF)) + 0x8000u;
        unsigned u1 = __float_as_uint(EXP2F(s[1] - EXPOFF)) + 0x8000u;
        unsigned u2 = __float_as_uint(EXP2F(s[2] - EXPOFF)) + 0x8000u;
        unsigned u3 = __float_as_uint(EXP2F(s[3] - EXPOFF)) + 0x8000u;
        uint2 pp;
        pp.x = __builtin_amdgcn_perm(u1, u0, 0x07060302u);
        pp.y = __builtin_amdgcn_perm(u3, u2, 0x07060302u);
        pf[ntj][ti] = __builtin_bit_cast(bf16x4, pp);
      }
    }

    // l += 1 * P^T
#pragma unroll
    for (int ks = 0; ks < 4; ks++)
#pragma unroll
      for (int ti = 0; ti < 2; ti++)
        lac[ti] = MFMA16(ones, pf[ks][ti], lac[ti]);

    // O^T += V^T * P^T  (V b128 = two MFMA16 A-frags via the store swizzle)
#pragma unroll
    for (int nt = 0; nt < 4; nt++) {
#pragma unroll
      for (int half = 0; half < 2; half++) {
        bf16x8 vv = *(const bf16x8*)(Vp + (size_t)(nt * 16) * SS + jb + half * 32);
        bf16x4 v0 = __builtin_shufflevector(vv, vv, 0, 1, 2, 3);
        bf16x4 v1 = __builtin_shufflevector(vv, vv, 4, 5, 6, 7);
#pragma unroll
        for (int ti = 0; ti < 2; ti++)
          o[ti][nt] = MFMA16(v0, pf[half * 2 + 0][ti], o[ti][nt]);
#pragma unroll
        for (int ti = 0; ti < 2; ti++)
          o[ti][nt] = MFMA16(v1, pf[half * 2 + 1][ti], o[ti][nt]);
      }
    }

    *(uint4*)&lK[(jt + 1) & 1][r0][cs] = kreg0;
    *(uint4*)&lK[(jt + 1) & 1][r1][cs] = kreg1;
  }

  // epilogue: write unnormalized fp32 partial O and partial l
#pragma unroll
  for (int ti = 0; ti < 2; ti++) {
    const int si = qrow0 + ti * 16 + lrow;
    float* dst = Op + ((size_t)(b * SS + si)) * D_MODEL + h * DH;
#pragma unroll
    for (int nt = 0; nt < 4; nt++)
      *(f32x4*)(dst + nt * 16 + quad * 4) = o[ti][nt];
    if (quad == 0)
      lp[(size_t)(b * SS + si) * NH + h] = lac[ti][0];
  }
}

// ---------------- launch ----------------
extern "C" void kernel_launch(void* const* d_in, const int* in_sizes, int n_in,
                              void* d_out, int out_size, void* d_ws, size_t ws_size,
                              hipStream_t stream) {
  const float* q  = (const float*)d_in[0];
  const float* k  = (const float*)d_in[1];
  const float* v  = (const float*)d_in[2];
  const float* Wq = (const float*)d_in[3];
  const float* bq = (const float*)d_in[4];
  const float* Wk = (const float*)d_in[5];
  const float* bk = (const float*)d_in[6];
  const float* Wv = (const float*)d_in[7];
  const float* bv = (const float*)d_in[8];
  const float* Wo = (const float*)d_in[9];
  const float* bo = (const float*)d_in[10];

  const size_t NX = (size_t)MTOT * D_MODEL;     // 4,194,304

  char* p = (char*)d_ws;
  unsigned short* Qh  = (unsigned short*)p; p += NX * 2;
  unsigned short* Kh  = (unsigned short*)p; p += NX * 2;
  unsigned short* Vtg = (unsigned short*)p; p += NX * 2;
  float* Oa = (float*)p; p += NX * 4;
  float* Ob = (float*)p; p += NX * 4;
  float* la = (float*)p; p += (size_t)MTOT * NH * 4;
  float* lb = (float*)p; p += (size_t)MTOT * NH * 4;

  GemmArgs pa;
  pa.A[0] = q; pa.A[1] = k; pa.A[2] = v;
  pa.W[0] = Wq; pa.W[1] = Wk; pa.W[2] = Wv;
  pa.bias[0] = bq; pa.bias[1] = bk; pa.bias[2] = bv;
  pa.out[0] = Qh; pa.out[1] = Kh; pa.out[2] = Vtg;
  pa.outf = nullptr;
  pa.Oa = nullptr; pa.Ob = nullptr; pa.la = nullptr; pa.lb = nullptr;
  pa.mode = 0;
  gemm_kernel<<<dim3(4, 128, 3), 256, 0, stream>>>(pa);

  attn_kernel<<<dim3(64, NH, BB), 256, 0, stream>>>(Qh, Kh, Vtg, Oa, Ob, la, lb);

  GemmArgs oa;
  oa.A[0] = nullptr; oa.A[1] = nullptr; oa.A[2] = nullptr;
  oa.W[0] = Wo; oa.W[1] = Wo; oa.W[2] = Wo;
  oa.bias[0] = bo; oa.bias[1] = bo; oa.bias[2] = bo;
  oa.out[0] = nullptr; oa.out[1] = nullptr; oa.out[2] = nullptr;
  oa.outf = (float*)d_out;
  oa.Oa = Oa; oa.Ob = Ob; oa.la = la; oa.lb = lb;
  oa.mode = 1;
  gemm_kernel<<<dim3(4, 128, 1), 256, 0, stream>>>(oa);
}